// Round 1
// baseline (553.466 us; speedup 1.0000x reference)
//
#include <hip/hip_runtime.h>
#include <hip/hip_bf16.h>
#include <cstdint>
#include <cstddef>

#define N_NODES 50000
#define N_EDGES 800000
#define DIM 64
#define N_REL 16
#define N_Q 8192

// ---------- helpers ----------
__device__ __forceinline__ float bcast_lane(float v, int l) {
    return __int_as_float(__builtin_amdgcn_readlane(__float_as_int(v), l));
}

__device__ __forceinline__ unsigned short f2bf_rn(float f) {
    unsigned int b = __float_as_uint(f);
    unsigned int r = (b + 0x7FFFu + ((b >> 16) & 1u)) >> 16;
    return (unsigned short)r;
}

__device__ __forceinline__ void store_xw4(float* p, const float v[4]) {
    *reinterpret_cast<float4*>(p) = make_float4(v[0], v[1], v[2], v[3]);
}
__device__ __forceinline__ void store_xw4(__hip_bfloat16* p, const float v[4]) {
    ushort4 u;
    u.x = f2bf_rn(v[0]); u.y = f2bf_rn(v[1]); u.z = f2bf_rn(v[2]); u.w = f2bf_rn(v[3]);
    *reinterpret_cast<ushort4*>(p) = u;
}
__device__ __forceinline__ float load_xw(const float* p) { return *p; }
__device__ __forceinline__ float load_xw(const __hip_bfloat16* p) {
    return __bfloat162float(*p);
}

// ---------- input projection: x0 = relu(node_feat @ in_w + in_b) ----------
__global__ __launch_bounds__(256) void k_input_proj(
    const float* __restrict__ nf, const float* __restrict__ inw,
    const float* __restrict__ inb, float* __restrict__ x0)
{
    int t = blockIdx.x * 256 + threadIdx.x;
    int n = t >> 6;
    if (n >= N_NODES) return;
    int o = t & 63;
    float4 f = *reinterpret_cast<const float4*>(nf + (size_t)n * 4);
    float acc = inb[o];
    acc += f.x * inw[0 * 64 + o];
    acc += f.y * inw[1 * 64 + o];
    acc += f.z * inw[2 * 64 + o];
    acc += f.w * inw[3 * 64 + o];
    x0[t] = acc > 0.f ? acc : 0.f;
}

// ---------- CSR build ----------
__global__ __launch_bounds__(256) void k_hist(const int* __restrict__ dst,
                                              int* __restrict__ counts)
{
    int e = blockIdx.x * 256 + threadIdx.x;
    if (e < N_EDGES) atomicAdd(&counts[dst[e]], 1);
}

// single-block exclusive scan over counts -> offs, woffs, deg(float, clamped>=1)
__global__ __launch_bounds__(1024) void k_scan(const int* __restrict__ counts,
                                               int* __restrict__ offs,
                                               int* __restrict__ woffs,
                                               float* __restrict__ deg, int n)
{
    __shared__ int wsum[16];
    __shared__ int chunk_total;
    int tid = threadIdx.x, lane = tid & 63, wid = tid >> 6;
    int running = 0;
    for (int base = 0; base < n; base += 1024) {
        int i = base + tid;
        int c = (i < n) ? counts[i] : 0;
        int v = c;
        #pragma unroll
        for (int off = 1; off < 64; off <<= 1) {
            int t = __shfl_up(v, off);
            if (lane >= off) v += t;
        }
        if (lane == 63) wsum[wid] = v;
        __syncthreads();
        if (wid == 0) {
            int wv = (lane < 16) ? wsum[lane] : 0;
            #pragma unroll
            for (int off = 1; off < 16; off <<= 1) {
                int t = __shfl_up(wv, off);
                if (lane >= off) wv += t;
            }
            if (lane < 16) wsum[lane] = wv;
            if (lane == 15) chunk_total = wv;
        }
        __syncthreads();
        int wbase = (wid == 0) ? 0 : wsum[wid - 1];
        int excl = running + v + wbase - c;
        if (i < n) {
            offs[i] = excl;
            woffs[i] = excl;
            deg[i] = (float)(c > 1 ? c : 1);
        }
        running += chunk_total;
        __syncthreads();
    }
    if (tid == 0) offs[n] = running;
}

__global__ __launch_bounds__(256) void k_fill(
    const int* __restrict__ src, const int* __restrict__ dst,
    const int* __restrict__ et, int* __restrict__ woffs,
    unsigned int* __restrict__ csr)
{
    int e = blockIdx.x * 256 + threadIdx.x;
    if (e >= N_EDGES) return;
    int d = dst[e];
    int pos = atomicAdd(&woffs[d], 1);
    csr[pos] = ((unsigned)src[e] << 4) | (unsigned)et[e];
}

// ---------- xw = x @ rel_w[l]  (M=50000, K=64, N=1024; block = 64 rows x one relation) ----------
template <typename T>
__global__ __launch_bounds__(256) void k_gemm_xw(
    const float* __restrict__ x, const float* __restrict__ relw_l,
    T* __restrict__ xw)
{
    __shared__ float xsT[64][68];  // [k][m], padded
    __shared__ float wsm[64][68];  // [k][n], padded
    const int mbase = blockIdx.x * 64;
    const int r = blockIdx.y;
    const int tid = threadIdx.x;
    const float* W = relw_l + (size_t)r * 4096;

    #pragma unroll
    for (int it = 0; it < 4; ++it) {
        int id = tid * 4 + it * 1024;
        int k = id >> 6, n = id & 63;
        float4 v = *reinterpret_cast<const float4*>(W + id);
        *reinterpret_cast<float4*>(&wsm[k][n]) = v;
    }
    #pragma unroll
    for (int it = 0; it < 4; ++it) {
        int id = tid * 4 + it * 1024;
        int m = id >> 6, d = id & 63;
        int row = mbase + m;
        float4 v = make_float4(0.f, 0.f, 0.f, 0.f);
        if (row < N_NODES)
            v = *reinterpret_cast<const float4*>(x + (size_t)row * 64 + d);
        xsT[d + 0][m] = v.x;
        xsT[d + 1][m] = v.y;
        xsT[d + 2][m] = v.z;
        xsT[d + 3][m] = v.w;
    }
    __syncthreads();

    const int tx = tid & 15, ty = tid >> 4;
    float acc[4][4] = {};
    #pragma unroll 8
    for (int k = 0; k < 64; ++k) {
        float4 a = *reinterpret_cast<const float4*>(&xsT[k][ty * 4]);
        float4 b = *reinterpret_cast<const float4*>(&wsm[k][tx * 4]);
        float av[4] = {a.x, a.y, a.z, a.w};
        float bv[4] = {b.x, b.y, b.z, b.w};
        #pragma unroll
        for (int i = 0; i < 4; ++i)
            #pragma unroll
            for (int j = 0; j < 4; ++j) acc[i][j] += av[i] * bv[j];
    }

    #pragma unroll
    for (int i = 0; i < 4; ++i) {
        int row = mbase + ty * 4 + i;
        if (row < N_NODES) {
            size_t o = (size_t)row * 1024 + r * 64 + tx * 4;
            store_xw4(xw + o, acc[i]);
        }
    }
}

// ---------- per-node update: x' = relu(x@self_w + b + (sum_in xw[src,type]) / deg) ----------
template <typename T>
__global__ __launch_bounds__(256) void k_node_update(
    const float* __restrict__ x, const T* __restrict__ xw,
    const int* __restrict__ offs, const unsigned int* __restrict__ csr,
    const float* __restrict__ deg, const float* __restrict__ selfw,
    const float* __restrict__ selfb, float* __restrict__ xout)
{
    int v = blockIdx.x * 4 + (threadIdx.x >> 6);
    if (v >= N_NODES) return;
    int lane = threadIdx.x & 63;
    float xv = x[(size_t)v * 64 + lane];
    float acc = selfb[lane];
    #pragma unroll 8
    for (int d = 0; d < 64; ++d) {
        float xd = bcast_lane(xv, d);
        acc += xd * selfw[d * 64 + lane];
    }
    float agg = 0.f;
    int e0 = offs[v], e1 = offs[v + 1];
    for (int i = e0; i < e1; ++i) {
        unsigned int cv = csr[i];
        const T* p = xw + (size_t)(cv >> 4) * 1024 + (cv & 15u) * 64 + lane;
        agg += load_xw(p);
    }
    float res = acc + agg / deg[v];
    xout[(size_t)v * 64 + lane] = res > 0.f ? res : 0.f;
}

// ---------- scoring ----------
__global__ __launch_bounds__(256) void k_score(
    const float* __restrict__ x, const int* __restrict__ heads,
    const int* __restrict__ rels, const int* __restrict__ tails,
    const float* __restrict__ rel_emb, const float* __restrict__ w1,
    const float* __restrict__ b1, const float* __restrict__ w2,
    const float* __restrict__ b2, float* __restrict__ out)
{
    int q = blockIdx.x * 4 + (threadIdx.x >> 6);
    if (q >= N_Q) return;
    int lane = threadIdx.x & 63;
    float zh = x[(size_t)heads[q] * 64 + lane];
    float zt = x[(size_t)tails[q] * 64 + lane];
    float re = rel_emb[(size_t)rels[q] * 64 + lane];
    float acc = b1[lane];
    #pragma unroll 8
    for (int k = 0; k < 64; ++k)
        acc += bcast_lane(zh, k) * w1[k * 64 + lane];
    #pragma unroll 8
    for (int k = 0; k < 64; ++k)
        acc += bcast_lane(zt, k) * w1[(64 + k) * 64 + lane];
    #pragma unroll 8
    for (int k = 0; k < 64; ++k)
        acc += bcast_lane(re, k) * w1[(128 + k) * 64 + lane];
    float h = acc > 0.f ? acc : 0.f;
    float p = h * w2[lane];
    #pragma unroll
    for (int off = 32; off > 0; off >>= 1) p += __shfl_xor(p, off);
    if (lane == 0) out[q] = p + b2[0];
}

// ---------- launch ----------
extern "C" void kernel_launch(void* const* d_in, const int* in_sizes, int n_in,
                              void* d_out, int out_size, void* d_ws, size_t ws_size,
                              hipStream_t stream)
{
    const float* node_feat = (const float*)d_in[0];
    const int* edge_index  = (const int*)d_in[1];
    const int* edge_type   = (const int*)d_in[2];
    const int* heads       = (const int*)d_in[3];
    const int* rels        = (const int*)d_in[4];
    const int* tails       = (const int*)d_in[5];
    const float* in_w      = (const float*)d_in[6];
    const float* in_b      = (const float*)d_in[7];
    const float* rel_w     = (const float*)d_in[8];
    const float* self_w    = (const float*)d_in[9];
    const float* self_b    = (const float*)d_in[10];
    const float* rel_emb   = (const float*)d_in[11];
    const float* sc_w1     = (const float*)d_in[12];
    const float* sc_b1     = (const float*)d_in[13];
    const float* sc_w2     = (const float*)d_in[14];
    const float* sc_b2     = (const float*)d_in[15];
    float* out = (float*)d_out;

    char* ws = (char*)d_ws;
    size_t off = 0;
    auto alloc = [&](size_t bytes) -> void* {
        void* p = ws + off;
        off = (off + bytes + 255) & ~(size_t)255;
        return p;
    };
    float* x0        = (float*)alloc((size_t)N_NODES * 64 * 4);
    float* x1        = (float*)alloc((size_t)N_NODES * 64 * 4);
    float* deg       = (float*)alloc((size_t)N_NODES * 4);
    int* counts      = (int*)alloc((size_t)N_NODES * 4);
    int* offs        = (int*)alloc((size_t)(N_NODES + 1) * 4);
    int* woffs       = (int*)alloc((size_t)N_NODES * 4);
    unsigned int* csr = (unsigned int*)alloc((size_t)N_EDGES * 4);
    size_t fixed = off;
    bool xw_fp32 = (ws_size >= fixed + (size_t)N_NODES * 1024 * 4);
    void* xw = ws + fixed;

    const int* src = edge_index;
    const int* dst = edge_index + N_EDGES;

    hipMemsetAsync(counts, 0, (size_t)N_NODES * 4, stream);
    k_input_proj<<<(N_NODES * 64 + 255) / 256, 256, 0, stream>>>(node_feat, in_w, in_b, x0);
    k_hist<<<(N_EDGES + 255) / 256, 256, 0, stream>>>(dst, counts);
    k_scan<<<1, 1024, 0, stream>>>(counts, offs, woffs, deg, N_NODES);
    k_fill<<<(N_EDGES + 255) / 256, 256, 0, stream>>>(src, dst, edge_type, woffs, csr);

    dim3 ggrid((N_NODES + 63) / 64, N_REL);
    int ugrid = (N_NODES + 3) / 4;
    if (xw_fp32) {
        float* xwp = (float*)xw;
        for (int l = 0; l < 2; ++l) {
            const float* xin = (l == 0) ? x0 : x1;
            float* xout = (l == 0) ? x1 : x0;
            k_gemm_xw<float><<<ggrid, 256, 0, stream>>>(xin, rel_w + (size_t)l * N_REL * 4096, xwp);
            k_node_update<float><<<ugrid, 256, 0, stream>>>(
                xin, xwp, offs, csr, deg, self_w + (size_t)l * 4096, self_b + l * 64, xout);
        }
    } else {
        __hip_bfloat16* xwp = (__hip_bfloat16*)xw;
        for (int l = 0; l < 2; ++l) {
            const float* xin = (l == 0) ? x0 : x1;
            float* xout = (l == 0) ? x1 : x0;
            k_gemm_xw<__hip_bfloat16><<<ggrid, 256, 0, stream>>>(xin, rel_w + (size_t)l * N_REL * 4096, xwp);
            k_node_update<__hip_bfloat16><<<ugrid, 256, 0, stream>>>(
                xin, xwp, offs, csr, deg, self_w + (size_t)l * 4096, self_b + l * 64, xout);
        }
    }
    k_score<<<(N_Q + 3) / 4, 256, 0, stream>>>(x0, heads, rels, tails, rel_emb,
                                               sc_w1, sc_b1, sc_w2, sc_b2, out);
}

// Round 2
// 339.799 us; speedup vs baseline: 1.6288x; 1.6288x over previous
//
#include <hip/hip_runtime.h>
#include <hip/hip_bf16.h>
#include <cstdint>
#include <cstddef>

#define N_NODES 50000
#define N_EDGES 800000
#define DIM 64
#define N_REL 16
#define N_Q 8192
#define NKEY (N_NODES * 16)
#define KDIM 1088   // 16 relations * 64 + 64 self
#define SROW 1096   // padded LDS row in bf16 elems (2192 B, breaks 128B-multiple stride)
#define TILE 16     // nodes per block

typedef __attribute__((ext_vector_type(8))) short bf16x8;
typedef __attribute__((ext_vector_type(4))) float f32x4;

__device__ __forceinline__ float bcast_lane(float v, int l) {
    return __int_as_float(__builtin_amdgcn_readlane(__float_as_int(v), l));
}
__device__ __forceinline__ unsigned short f2bf(float f) {
    unsigned int b = __float_as_uint(f);
    return (unsigned short)((b + 0x7FFFu + ((b >> 16) & 1u)) >> 16);
}
__device__ __forceinline__ float bf2f(unsigned short u) {
    return __uint_as_float(((unsigned int)u) << 16);
}

// ---------- input projection -> bf16 x ----------
__global__ __launch_bounds__(256) void k_input_proj(
    const float* __restrict__ nf, const float* __restrict__ inw,
    const float* __restrict__ inb, unsigned short* __restrict__ xbf)
{
    int t = blockIdx.x * 256 + threadIdx.x;
    if (t >= N_NODES * 64) return;
    int n = t >> 6, o = t & 63;
    float4 f = *reinterpret_cast<const float4*>(nf + (size_t)n * 4);
    float a = inb[o] + f.x * inw[o] + f.y * inw[64 + o] + f.z * inw[128 + o] + f.w * inw[192 + o];
    xbf[t] = f2bf(a > 0.f ? a : 0.f);
}

// ---------- weight prep: WT[l][col][k] bf16, k = r*64+d (rel) then 1024+d (self) ----------
__global__ __launch_bounds__(256) void k_wprep(
    const float* __restrict__ rel_w, const float* __restrict__ self_w,
    unsigned short* __restrict__ wt)
{
    int i = blockIdx.x * 256 + threadIdx.x;
    if (i >= 2 * 64 * KDIM) return;
    int l = i / (64 * KDIM);
    int rem = i - l * (64 * KDIM);
    int c = rem / KDIM, k = rem - c * KDIM;
    float v;
    if (k < 1024) {
        int r = k >> 6, d = k & 63;
        v = rel_w[(((size_t)l * 16 + r) * 64 + d) * 64 + c];
    } else {
        int d = k - 1024;
        v = self_w[((size_t)l * 64 + d) * 64 + c];
    }
    wt[i] = f2bf(v);
}

// ---------- CSR build over key = dst*16 + rel ----------
__global__ __launch_bounds__(256) void k_hist16(
    const int* __restrict__ dst, const int* __restrict__ et, int* __restrict__ cnt)
{
    int e = blockIdx.x * 256 + threadIdx.x;
    if (e < N_EDGES) atomicAdd(&cnt[dst[e] * 16 + et[e]], 1);
}

// scan part A: each block scans 4096 elems (16/thread), writes local-exclusive + block total
__global__ __launch_bounds__(256) void k_scanA(
    const int* __restrict__ cnt, int* __restrict__ offs, int* __restrict__ part)
{
    int t = threadIdx.x;
    size_t base = (size_t)blockIdx.x * 4096 + (size_t)t * 16;
    bool ok = base < (size_t)NKEY;  // NKEY % 16 == 0, so whole-thread granularity
    int v[16];
    if (ok) {
        #pragma unroll
        for (int q = 0; q < 4; ++q)
            *reinterpret_cast<int4*>(&v[q * 4]) = *reinterpret_cast<const int4*>(&cnt[base + q * 4]);
    } else {
        #pragma unroll
        for (int j = 0; j < 16; ++j) v[j] = 0;
    }
    int run = 0;
    #pragma unroll
    for (int j = 0; j < 16; ++j) { int c = v[j]; v[j] = run; run += c; }
    int lane = t & 63, wid = t >> 6;
    int incl = run;
    #pragma unroll
    for (int o = 1; o < 64; o <<= 1) { int u = __shfl_up(incl, o); if (lane >= o) incl += u; }
    __shared__ int wtot[4], wbase[4];
    if (lane == 63) wtot[wid] = incl;
    __syncthreads();
    if (t == 0) { int r = 0; for (int w = 0; w < 4; ++w) { wbase[w] = r; r += wtot[w]; } part[blockIdx.x] = r; }
    __syncthreads();
    int texcl = wbase[wid] + incl - run;
    if (ok) {
        #pragma unroll
        for (int j = 0; j < 16; ++j) offs[base + j] = texcl + v[j];
    }
}

__global__ __launch_bounds__(256) void k_scanB(int* __restrict__ part, int n)
{
    __shared__ int tmp[256];
    int t = threadIdx.x;
    int v = (t < n) ? part[t] : 0;
    tmp[t] = v;
    __syncthreads();
    for (int o = 1; o < 256; o <<= 1) {
        int u = (t >= o) ? tmp[t - o] : 0;
        __syncthreads();
        tmp[t] += u;
        __syncthreads();
    }
    if (t < n) part[t] = tmp[t] - v;  // exclusive
}

__global__ __launch_bounds__(256) void k_scanC(
    int* __restrict__ offs, const int* __restrict__ part, int* __restrict__ woffs)
{
    int i = blockIdx.x * 256 + threadIdx.x;
    if (i < NKEY) {
        int v = offs[i] + part[i >> 12];
        offs[i] = v;
        woffs[i] = v;
    } else if (i == NKEY) {
        offs[i] = N_EDGES;
    }
}

__global__ __launch_bounds__(256) void k_fill16(
    const int* __restrict__ src, const int* __restrict__ dst, const int* __restrict__ et,
    int* __restrict__ woffs, unsigned int* __restrict__ csr)
{
    int e = blockIdx.x * 256 + threadIdx.x;
    if (e >= N_EDGES) return;
    int key = dst[e] * 16 + et[e];
    int pos = atomicAdd(&woffs[key], 1);
    csr[pos] = ((unsigned)src[e] << 4) | (unsigned)et[e];
}

// ---------- fused layer: gather-accumulate S tile in LDS, then MFMA with concat weights ----------
__global__ __launch_bounds__(256) void k_layer(
    const unsigned short* __restrict__ xbf_in,
    const int* __restrict__ offs,
    const unsigned int* __restrict__ csr,
    const unsigned short* __restrict__ wt,    // this layer: [64 cols][KDIM] bf16
    const float* __restrict__ selfb,          // [64]
    unsigned short* __restrict__ xbf_out,
    float* __restrict__ xf_out)
{
    __shared__ unsigned short S[TILE * SROW];
    const int tid = threadIdx.x, lane = tid & 63, wid = tid >> 6;
    const int nb = blockIdx.x * TILE;

    // zero S (16B stores)
    for (int i = tid; i < TILE * SROW / 8; i += 256)
        *reinterpret_cast<uint4*>(&S[i * 8]) = make_uint4(0, 0, 0, 0);
    __syncthreads();

    // phase A: each wave fills 4 node rows
    #pragma unroll 1
    for (int i = 0; i < 4; ++i) {
        const int nl = wid * 4 + i;
        const int node = nb + nl;
        const int e0 = offs[node * 16];
        const int e1 = offs[node * 16 + 16];
        const int degc = e1 - e0;
        const float inv = 1.0f / (float)(degc > 1 ? degc : 1);
        int cur = -1;
        float acc = 0.f;
        for (int base = e0; base < e1; base += 8) {
            unsigned int cv[8];
            float xv[8];
            #pragma unroll
            for (int j = 0; j < 8; ++j) {
                int e = base + j;
                cv[j] = (e < e1) ? csr[e] : 0xFFFFFFFFu;
            }
            #pragma unroll
            for (int j = 0; j < 8; ++j) {
                unsigned s = (cv[j] != 0xFFFFFFFFu) ? (cv[j] >> 4) : 0u;
                xv[j] = bf2f(xbf_in[(size_t)s * 64 + lane]);
            }
            #pragma unroll
            for (int j = 0; j < 8; ++j) {
                if (cv[j] == 0xFFFFFFFFu) continue;
                int r = (int)(cv[j] & 15u);
                if (r != cur) {
                    if (cur >= 0) S[nl * SROW + cur * 64 + lane] = f2bf(acc * inv);
                    cur = r;
                    acc = 0.f;
                }
                acc += xv[j];
            }
        }
        if (cur >= 0) S[nl * SROW + cur * 64 + lane] = f2bf(acc * inv);
        // self slot (unscaled)
        S[nl * SROW + 1024 + lane] = xbf_in[(size_t)node * 64 + lane];
    }
    __syncthreads();

    // phase B: wave wid computes output cols [wid*16, wid*16+16) for all 16 nodes
    f32x4 acc4 = {0.f, 0.f, 0.f, 0.f};
    const int colg = lane & 15, kg = lane >> 4;
    const int col = wid * 16 + colg;
    const unsigned short* wcol = wt + (size_t)col * KDIM + kg * 8;
    const unsigned short* srow = &S[(lane & 15) * SROW + kg * 8];
    #pragma unroll 4
    for (int k0 = 0; k0 < KDIM; k0 += 32) {
        bf16x8 a = *reinterpret_cast<const bf16x8*>(srow + k0);
        bf16x8 b = *reinterpret_cast<const bf16x8*>(wcol + k0);
        acc4 = __builtin_amdgcn_mfma_f32_16x16x32_bf16(a, b, acc4, 0, 0, 0);
    }
    const float sb = selfb[col];
    #pragma unroll
    for (int j = 0; j < 4; ++j) {
        int row = kg * 4 + j;
        int node = nb + row;
        float v = acc4[j] + sb;
        v = v > 0.f ? v : 0.f;
        xf_out[(size_t)node * 64 + col] = v;
        xbf_out[(size_t)node * 64 + col] = f2bf(v);
    }
}

// ---------- scoring (fp32) ----------
__global__ __launch_bounds__(256) void k_score(
    const float* __restrict__ x, const int* __restrict__ heads,
    const int* __restrict__ rels, const int* __restrict__ tails,
    const float* __restrict__ rel_emb, const float* __restrict__ w1,
    const float* __restrict__ b1, const float* __restrict__ w2,
    const float* __restrict__ b2, float* __restrict__ out)
{
    int q = blockIdx.x * 4 + (threadIdx.x >> 6);
    if (q >= N_Q) return;
    int lane = threadIdx.x & 63;
    float zh = x[(size_t)heads[q] * 64 + lane];
    float zt = x[(size_t)tails[q] * 64 + lane];
    float re = rel_emb[(size_t)rels[q] * 64 + lane];
    float acc = b1[lane];
    #pragma unroll 8
    for (int k = 0; k < 64; ++k)
        acc += bcast_lane(zh, k) * w1[k * 64 + lane];
    #pragma unroll 8
    for (int k = 0; k < 64; ++k)
        acc += bcast_lane(zt, k) * w1[(64 + k) * 64 + lane];
    #pragma unroll 8
    for (int k = 0; k < 64; ++k)
        acc += bcast_lane(re, k) * w1[(128 + k) * 64 + lane];
    float h = acc > 0.f ? acc : 0.f;
    float p = h * w2[lane];
    #pragma unroll
    for (int off = 32; off > 0; off >>= 1) p += __shfl_xor(p, off);
    if (lane == 0) out[q] = p + b2[0];
}

// ---------- launch ----------
extern "C" void kernel_launch(void* const* d_in, const int* in_sizes, int n_in,
                              void* d_out, int out_size, void* d_ws, size_t ws_size,
                              hipStream_t stream)
{
    const float* node_feat = (const float*)d_in[0];
    const int* edge_index  = (const int*)d_in[1];
    const int* edge_type   = (const int*)d_in[2];
    const int* heads       = (const int*)d_in[3];
    const int* rels        = (const int*)d_in[4];
    const int* tails       = (const int*)d_in[5];
    const float* in_w      = (const float*)d_in[6];
    const float* in_b      = (const float*)d_in[7];
    const float* rel_w     = (const float*)d_in[8];
    const float* self_w    = (const float*)d_in[9];
    const float* self_b    = (const float*)d_in[10];
    const float* rel_emb   = (const float*)d_in[11];
    const float* sc_w1     = (const float*)d_in[12];
    const float* sc_b1     = (const float*)d_in[13];
    const float* sc_w2     = (const float*)d_in[14];
    const float* sc_b2     = (const float*)d_in[15];
    float* out = (float*)d_out;

    char* ws = (char*)d_ws;
    size_t off = 0;
    auto alloc = [&](size_t bytes) -> void* {
        void* p = ws + off;
        off = (off + bytes + 255) & ~(size_t)255;
        return p;
    };
    unsigned short* xbf_a = (unsigned short*)alloc((size_t)N_NODES * 64 * 2);
    unsigned short* xbf_b = (unsigned short*)alloc((size_t)N_NODES * 64 * 2);
    float* xf             = (float*)alloc((size_t)N_NODES * 64 * 4);
    int* cnt              = (int*)alloc((size_t)NKEY * 4);
    int* offs             = (int*)alloc((size_t)(NKEY + 1) * 4);
    int* woffs            = (int*)alloc((size_t)NKEY * 4);
    unsigned int* csr     = (unsigned int*)alloc((size_t)N_EDGES * 4);
    unsigned short* wt    = (unsigned short*)alloc((size_t)2 * 64 * KDIM * 2);
    int* part             = (int*)alloc(1024);

    const int* src = edge_index;
    const int* dst = edge_index + N_EDGES;

    const int nscan = (NKEY + 4095) / 4096;  // 196

    hipMemsetAsync(cnt, 0, (size_t)NKEY * 4, stream);
    k_input_proj<<<(N_NODES * 64 + 255) / 256, 256, 0, stream>>>(node_feat, in_w, in_b, xbf_a);
    k_wprep<<<(2 * 64 * KDIM + 255) / 256, 256, 0, stream>>>(rel_w, self_w, wt);
    k_hist16<<<(N_EDGES + 255) / 256, 256, 0, stream>>>(dst, edge_type, cnt);
    k_scanA<<<nscan, 256, 0, stream>>>(cnt, offs, part);
    k_scanB<<<1, 256, 0, stream>>>(part, nscan);
    k_scanC<<<(NKEY + 1 + 255) / 256, 256, 0, stream>>>(offs, part, woffs);
    k_fill16<<<(N_EDGES + 255) / 256, 256, 0, stream>>>(src, dst, edge_type, woffs, csr);

    for (int l = 0; l < 2; ++l) {
        const unsigned short* xin = (l == 0) ? xbf_a : xbf_b;
        unsigned short* xout = (l == 0) ? xbf_b : xbf_a;
        k_layer<<<N_NODES / TILE, 256, 0, stream>>>(
            xin, offs, csr, wt + (size_t)l * 64 * KDIM, self_b + l * 64, xout, xf);
    }
    k_score<<<(N_Q + 3) / 4, 256, 0, stream>>>(xf, heads, rels, tails, rel_emb,
                                               sc_w1, sc_b1, sc_w2, sc_b2, out);
}

// Round 5
// 274.822 us; speedup vs baseline: 2.0139x; 1.2364x over previous
//
#include <hip/hip_runtime.h>
#include <hip/hip_bf16.h>
#include <cstdint>
#include <cstddef>

#define N_NODES 50000
#define N_EDGES 800000
#define DIM 64
#define N_REL 16
#define N_Q 8192
#define NKEY (N_NODES * 16)
#define KDIM 1088   // 16 relations * 64 + 64 self
#define SROW 1096   // padded LDS row in bf16 elems
#define TILE 16     // nodes per block (= waves per block)

typedef __attribute__((ext_vector_type(8))) short bf16x8;
typedef __attribute__((ext_vector_type(4))) float f32x4;

__device__ __forceinline__ float bcast_lane(float v, int l) {
    return __int_as_float(__builtin_amdgcn_readlane(__float_as_int(v), l));
}
__device__ __forceinline__ unsigned short f2bf(float f) {
    unsigned int b = __float_as_uint(f);
    return (unsigned short)((b + 0x7FFFu + ((b >> 16) & 1u)) >> 16);
}
__device__ __forceinline__ float bf2f(unsigned short u) {
    return __uint_as_float(((unsigned int)u) << 16);
}

// ---------- input projection -> bf16 x ----------
__global__ __launch_bounds__(256) void k_input_proj(
    const float* __restrict__ nf, const float* __restrict__ inw,
    const float* __restrict__ inb, unsigned short* __restrict__ xbf)
{
    int t = blockIdx.x * 256 + threadIdx.x;
    if (t >= N_NODES * 64) return;
    int n = t >> 6, o = t & 63;
    float4 f = *reinterpret_cast<const float4*>(nf + (size_t)n * 4);
    float a = inb[o] + f.x * inw[o] + f.y * inw[64 + o] + f.z * inw[128 + o] + f.w * inw[192 + o];
    xbf[t] = f2bf(a > 0.f ? a : 0.f);
}

// ---------- weight prep: WT[l][col][k] bf16, k = r*64+d (rel) then 1024+d (self) ----------
__global__ __launch_bounds__(256) void k_wprep(
    const float* __restrict__ rel_w, const float* __restrict__ self_w,
    unsigned short* __restrict__ wt)
{
    int i = blockIdx.x * 256 + threadIdx.x;
    if (i >= 2 * 64 * KDIM) return;
    int l = i / (64 * KDIM);
    int rem = i - l * (64 * KDIM);
    int c = rem / KDIM, k = rem - c * KDIM;
    float v;
    if (k < 1024) {
        int r = k >> 6, d = k & 63;
        v = rel_w[(((size_t)l * 16 + r) * 64 + d) * 64 + c];
    } else {
        int d = k - 1024;
        v = self_w[((size_t)l * 64 + d) * 64 + c];
    }
    wt[i] = f2bf(v);
}

// ---------- CSR build over key = dst*16 + rel ----------
__global__ __launch_bounds__(256) void k_hist16(
    const int* __restrict__ dst, const int* __restrict__ et, int* __restrict__ cnt)
{
    int e = blockIdx.x * 256 + threadIdx.x;
    if (e < N_EDGES) atomicAdd(&cnt[dst[e] * 16 + et[e]], 1);
}

__global__ __launch_bounds__(256) void k_scanA(
    const int* __restrict__ cnt, int* __restrict__ offs, int* __restrict__ part)
{
    int t = threadIdx.x;
    size_t base = (size_t)blockIdx.x * 4096 + (size_t)t * 16;
    bool ok = base < (size_t)NKEY;
    int v[16];
    if (ok) {
        #pragma unroll
        for (int q = 0; q < 4; ++q)
            *reinterpret_cast<int4*>(&v[q * 4]) = *reinterpret_cast<const int4*>(&cnt[base + q * 4]);
    } else {
        #pragma unroll
        for (int j = 0; j < 16; ++j) v[j] = 0;
    }
    int run = 0;
    #pragma unroll
    for (int j = 0; j < 16; ++j) { int c = v[j]; v[j] = run; run += c; }
    int lane = t & 63, wid = t >> 6;
    int incl = run;
    #pragma unroll
    for (int o = 1; o < 64; o <<= 1) { int u = __shfl_up(incl, o); if (lane >= o) incl += u; }
    __shared__ int wtot[4], wbase[4];
    if (lane == 63) wtot[wid] = incl;
    __syncthreads();
    if (t == 0) { int r = 0; for (int w = 0; w < 4; ++w) { wbase[w] = r; r += wtot[w]; } part[blockIdx.x] = r; }
    __syncthreads();
    int texcl = wbase[wid] + incl - run;
    if (ok) {
        #pragma unroll
        for (int j = 0; j < 16; ++j) offs[base + j] = texcl + v[j];
    }
}

__global__ __launch_bounds__(256) void k_scanB(int* __restrict__ part, int n)
{
    __shared__ int tmp[256];
    int t = threadIdx.x;
    int v = (t < n) ? part[t] : 0;
    tmp[t] = v;
    __syncthreads();
    for (int o = 1; o < 256; o <<= 1) {
        int u = (t >= o) ? tmp[t - o] : 0;
        __syncthreads();
        tmp[t] += u;
        __syncthreads();
    }
    if (t < n) part[t] = tmp[t] - v;
}

__global__ __launch_bounds__(256) void k_scanC(
    int* __restrict__ offs, const int* __restrict__ part, int* __restrict__ woffs)
{
    int i = blockIdx.x * 256 + threadIdx.x;
    if (i < NKEY) {
        int v = offs[i] + part[i >> 12];
        offs[i] = v;
        woffs[i] = v;
    } else if (i == NKEY) {
        offs[i] = N_EDGES;
    }
}

__global__ __launch_bounds__(256) void k_fill16(
    const int* __restrict__ src, const int* __restrict__ dst, const int* __restrict__ et,
    int* __restrict__ woffs, unsigned int* __restrict__ csr)
{
    int e = blockIdx.x * 256 + threadIdx.x;
    if (e >= N_EDGES) return;
    int key = dst[e] * 16 + et[e];
    int pos = atomicAdd(&woffs[key], 1);
    csr[pos] = ((unsigned)src[e] << 4) | (unsigned)et[e];
}

// ---------- fused layer: one wave per node, 16 waves/block ----------
__global__ __launch_bounds__(1024, 8) void k_layer(
    const unsigned short* __restrict__ xbf_in,
    const int* __restrict__ offs,
    const unsigned int* __restrict__ csr,
    const unsigned short* __restrict__ wt,    // this layer: [64 cols][KDIM] bf16
    const float* __restrict__ selfb,          // [64]
    unsigned short* __restrict__ xbf_out)
{
    __shared__ unsigned short S[TILE * SROW];
    const int tid = threadIdx.x, lane = tid & 63, wid = tid >> 6;
    const int nb = blockIdx.x * TILE;
    const int node = nb + wid;

    // issue early: offs + self row
    const int e0 = offs[node * 16];
    const int e1 = offs[node * 16 + 16];
    const unsigned short xself = xbf_in[(size_t)node * 64 + lane];

    // each wave zeroes its own S row (first 1088 elems = 544 dwords), no barrier needed
    {
        unsigned int* Sr = reinterpret_cast<unsigned int*>(&S[wid * SROW]);
        #pragma unroll
        for (int i = 0; i < 8; ++i) Sr[lane + i * 64] = 0u;
        if (lane < 32) Sr[512 + lane] = 0u;
    }

    const int degc = e1 - e0;
    const float inv = 1.0f / (float)(degc > 1 ? degc : 1);
    int cur = -1;
    float acc = 0.f;
    for (int base = e0; base < e1; base += 16) {
        const int rem = e1 - base;  // > 0, wave-uniform
        int ci = base + (lane & 15);
        ci = ci < (N_EDGES - 1) ? ci : (N_EDGES - 1);
        const unsigned int ecv = csr[ci];

        unsigned int cv[16];
        float xj[16];
        #pragma unroll
        for (int j = 0; j < 16; ++j) {
            cv[j] = (unsigned)__builtin_amdgcn_readlane((int)ecv, j);
            unsigned sj = (j < rem) ? (cv[j] >> 4) : 0u;  // dummy -> row 0 (L1-hot)
            xj[j] = bf2f(xbf_in[(size_t)sj * 64 + lane]);
        }
        #pragma unroll
        for (int j = 0; j < 16; ++j) {
            if (j < rem) {
                int rj = (int)(cv[j] & 15u);
                if (rj != cur) {
                    if (cur >= 0) S[wid * SROW + cur * 64 + lane] = f2bf(acc * inv);
                    cur = rj;
                    acc = 0.f;
                }
                acc += xj[j];
            }
        }
    }
    if (cur >= 0) S[wid * SROW + cur * 64 + lane] = f2bf(acc * inv);
    S[wid * SROW + 1024 + lane] = xself;
    __syncthreads();

    // phase B: waves 0..3 compute output cols [wid*16, wid*16+16) for all 16 nodes
    if (wid >= 4) return;
    f32x4 acc4 = {0.f, 0.f, 0.f, 0.f};
    const int colg = lane & 15, kg = lane >> 4;
    const int col = wid * 16 + colg;
    const unsigned short* wcol = wt + (size_t)col * KDIM + kg * 8;
    const unsigned short* srow = &S[colg * SROW + kg * 8];
    #pragma unroll 2
    for (int k0 = 0; k0 < KDIM; k0 += 32) {
        bf16x8 a = *reinterpret_cast<const bf16x8*>(srow + k0);
        bf16x8 b = *reinterpret_cast<const bf16x8*>(wcol + k0);
        acc4 = __builtin_amdgcn_mfma_f32_16x16x32_bf16(a, b, acc4, 0, 0, 0);
    }
    const float sb = selfb[col];
    #pragma unroll
    for (int j = 0; j < 4; ++j) {
        int row = kg * 4 + j;
        float v = acc4[j] + sb;
        v = v > 0.f ? v : 0.f;
        xbf_out[(size_t)(nb + row) * 64 + col] = f2bf(v);
    }
}

// ---------- scoring (reads bf16 x) ----------
__global__ __launch_bounds__(256) void k_score(
    const unsigned short* __restrict__ x, const int* __restrict__ heads,
    const int* __restrict__ rels, const int* __restrict__ tails,
    const float* __restrict__ rel_emb, const float* __restrict__ w1,
    const float* __restrict__ b1, const float* __restrict__ w2,
    const float* __restrict__ b2, float* __restrict__ out)
{
    int q = blockIdx.x * 4 + (threadIdx.x >> 6);
    if (q >= N_Q) return;
    int lane = threadIdx.x & 63;
    float zh = bf2f(x[(size_t)heads[q] * 64 + lane]);
    float zt = bf2f(x[(size_t)tails[q] * 64 + lane]);
    float re = rel_emb[(size_t)rels[q] * 64 + lane];
    float acc = b1[lane];
    #pragma unroll 8
    for (int k = 0; k < 64; ++k)
        acc += bcast_lane(zh, k) * w1[k * 64 + lane];
    #pragma unroll 8
    for (int k = 0; k < 64; ++k)
        acc += bcast_lane(zt, k) * w1[(64 + k) * 64 + lane];
    #pragma unroll 8
    for (int k = 0; k < 64; ++k)
        acc += bcast_lane(re, k) * w1[(128 + k) * 64 + lane];
    float h = acc > 0.f ? acc : 0.f;
    float p = h * w2[lane];
    #pragma unroll
    for (int off = 32; off > 0; off >>= 1) p += __shfl_xor(p, off);
    if (lane == 0) out[q] = p + b2[0];
}

// ---------- launch ----------
extern "C" void kernel_launch(void* const* d_in, const int* in_sizes, int n_in,
                              void* d_out, int out_size, void* d_ws, size_t ws_size,
                              hipStream_t stream)
{
    const float* node_feat = (const float*)d_in[0];
    const int* edge_index  = (const int*)d_in[1];
    const int* edge_type   = (const int*)d_in[2];
    const int* heads       = (const int*)d_in[3];
    const int* rels        = (const int*)d_in[4];
    const int* tails       = (const int*)d_in[5];
    const float* in_w      = (const float*)d_in[6];
    const float* in_b      = (const float*)d_in[7];
    const float* rel_w     = (const float*)d_in[8];
    const float* self_w    = (const float*)d_in[9];
    const float* self_b    = (const float*)d_in[10];
    const float* rel_emb   = (const float*)d_in[11];
    const float* sc_w1     = (const float*)d_in[12];
    const float* sc_b1     = (const float*)d_in[13];
    const float* sc_w2     = (const float*)d_in[14];
    const float* sc_b2     = (const float*)d_in[15];
    float* out = (float*)d_out;

    char* ws = (char*)d_ws;
    size_t off = 0;
    auto alloc = [&](size_t bytes) -> void* {
        void* p = ws + off;
        off = (off + bytes + 255) & ~(size_t)255;
        return p;
    };
    unsigned short* xbf_a = (unsigned short*)alloc((size_t)N_NODES * 64 * 2);
    unsigned short* xbf_b = (unsigned short*)alloc((size_t)N_NODES * 64 * 2);
    int* cnt              = (int*)alloc((size_t)NKEY * 4);
    int* offs             = (int*)alloc((size_t)(NKEY + 1) * 4);
    int* woffs            = (int*)alloc((size_t)NKEY * 4);
    unsigned int* csr     = (unsigned int*)alloc((size_t)N_EDGES * 4);
    unsigned short* wt    = (unsigned short*)alloc((size_t)2 * 64 * KDIM * 2);
    int* part             = (int*)alloc(1024);

    const int* src = edge_index;
    const int* dst = edge_index + N_EDGES;

    const int nscan = (NKEY + 4095) / 4096;  // 196

    hipMemsetAsync(cnt, 0, (size_t)NKEY * 4, stream);
    k_input_proj<<<(N_NODES * 64 + 255) / 256, 256, 0, stream>>>(node_feat, in_w, in_b, xbf_a);
    k_wprep<<<(2 * 64 * KDIM + 255) / 256, 256, 0, stream>>>(rel_w, self_w, wt);
    k_hist16<<<(N_EDGES + 255) / 256, 256, 0, stream>>>(dst, edge_type, cnt);
    k_scanA<<<nscan, 256, 0, stream>>>(cnt, offs, part);
    k_scanB<<<1, 256, 0, stream>>>(part, nscan);
    k_scanC<<<(NKEY + 1 + 255) / 256, 256, 0, stream>>>(offs, part, woffs);
    k_fill16<<<(N_EDGES + 255) / 256, 256, 0, stream>>>(src, dst, edge_type, woffs, csr);

    for (int l = 0; l < 2; ++l) {
        const unsigned short* xin = (l == 0) ? xbf_a : xbf_b;
        unsigned short* xout = (l == 0) ? xbf_b : xbf_a;
        k_layer<<<N_NODES / TILE, 1024, 0, stream>>>(
            xin, offs, csr, wt + (size_t)l * 64 * KDIM, self_b + l * 64, xout);
    }
    k_score<<<(N_Q + 3) / 4, 256, 0, stream>>>(xbf_a, heads, rels, tails, rel_emb,
                                               sc_w1, sc_b1, sc_w2, sc_b2, out);
}

// Round 6
// 235.698 us; speedup vs baseline: 2.3482x; 1.1660x over previous
//
#include <hip/hip_runtime.h>
#include <hip/hip_bf16.h>
#include <cstdint>
#include <cstddef>

#define N_NODES 50000
#define N_EDGES 800000
#define DIM 64
#define N_REL 16
#define N_Q 8192
#define NKEY (N_NODES * 16)
#define KDIM 1088   // 16 relations * 64 + 64 self
#define SROW 1096   // padded LDS row in bf16 elems
#define TILE 32     // nodes per block (2 per wave)
#define NKB 34      // K blocks of 32 (KDIM/32)
#define WTL (4 * NKB * 512)  // per-layer packed wt elems (4 colgrps * 34 kblocks * 64 lanes * 8)

typedef __attribute__((ext_vector_type(8))) short bf16x8;
typedef __attribute__((ext_vector_type(4))) float f32x4;

__device__ __forceinline__ float bcast_lane(float v, int l) {
    return __int_as_float(__builtin_amdgcn_readlane(__float_as_int(v), l));
}
__device__ __forceinline__ unsigned short f2bf(float f) {
    unsigned int b = __float_as_uint(f);
    return (unsigned short)((b + 0x7FFFu + ((b >> 16) & 1u)) >> 16);
}
__device__ __forceinline__ float bf2f(unsigned short u) {
    return __uint_as_float(((unsigned int)u) << 16);
}

// ---------- input projection -> bf16 x ----------
__global__ __launch_bounds__(256) void k_input_proj(
    const float* __restrict__ nf, const float* __restrict__ inw,
    const float* __restrict__ inb, unsigned short* __restrict__ xbf)
{
    int t = blockIdx.x * 256 + threadIdx.x;
    if (t >= N_NODES * 64) return;
    int n = t >> 6, o = t & 63;
    float4 f = *reinterpret_cast<const float4*>(nf + (size_t)n * 4);
    float a = inb[o] + f.x * inw[o] + f.y * inw[64 + o] + f.z * inw[128 + o] + f.w * inw[192 + o];
    xbf[t] = f2bf(a > 0.f ? a : 0.f);
}

// ---------- weight prep: packed MFMA B-fragment order ----------
// wtp[l][g(colgrp 0..3)][t(kblock 0..33)][lane 0..63][j 0..7]
//   = W[k = t*32 + (lane>>4)*8 + j][col = g*16 + (lane&15)]
// where W[k][c]: k<1024 -> rel_w[l][k>>6][k&63][c]; else self_w[l][k-1024][c]
__global__ __launch_bounds__(256) void k_wprep(
    const float* __restrict__ rel_w, const float* __restrict__ self_w,
    unsigned short* __restrict__ wt)
{
    int i = blockIdx.x * 256 + threadIdx.x;
    if (i >= 2 * WTL) return;
    int j = i & 7;
    int lane = (i >> 3) & 63;
    int rest = i >> 9;          // l*136 + g*34 + t
    int t = rest % NKB;
    int gl = rest / NKB;        // l*4 + g
    int g = gl & 3;
    int l = gl >> 2;
    int col = g * 16 + (lane & 15);
    int k = t * 32 + (lane >> 4) * 8 + j;
    float v;
    if (k < 1024) {
        int r = k >> 6, d = k & 63;
        v = rel_w[(((size_t)l * 16 + r) * 64 + d) * 64 + col];
    } else {
        int d = k - 1024;
        v = self_w[((size_t)l * 64 + d) * 64 + col];
    }
    wt[i] = f2bf(v);
}

// ---------- CSR build over key = dst*16 + rel ----------
__global__ __launch_bounds__(256) void k_hist16(
    const int* __restrict__ dst, const int* __restrict__ et, int* __restrict__ cnt)
{
    int e = blockIdx.x * 256 + threadIdx.x;
    if (e < N_EDGES) atomicAdd(&cnt[dst[e] * 16 + et[e]], 1);
}

__global__ __launch_bounds__(256) void k_scanA(
    const int* __restrict__ cnt, int* __restrict__ offs, int* __restrict__ part)
{
    int t = threadIdx.x;
    size_t base = (size_t)blockIdx.x * 4096 + (size_t)t * 16;
    bool ok = base < (size_t)NKEY;
    int v[16];
    if (ok) {
        #pragma unroll
        for (int q = 0; q < 4; ++q)
            *reinterpret_cast<int4*>(&v[q * 4]) = *reinterpret_cast<const int4*>(&cnt[base + q * 4]);
    } else {
        #pragma unroll
        for (int j = 0; j < 16; ++j) v[j] = 0;
    }
    int run = 0;
    #pragma unroll
    for (int j = 0; j < 16; ++j) { int c = v[j]; v[j] = run; run += c; }
    int lane = t & 63, wid = t >> 6;
    int incl = run;
    #pragma unroll
    for (int o = 1; o < 64; o <<= 1) { int u = __shfl_up(incl, o); if (lane >= o) incl += u; }
    __shared__ int wtot[4], wbase[4];
    if (lane == 63) wtot[wid] = incl;
    __syncthreads();
    if (t == 0) { int r = 0; for (int w = 0; w < 4; ++w) { wbase[w] = r; r += wtot[w]; } part[blockIdx.x] = r; }
    __syncthreads();
    int texcl = wbase[wid] + incl - run;
    if (ok) {
        #pragma unroll
        for (int j = 0; j < 16; ++j) offs[base + j] = texcl + v[j];
    }
}

__global__ __launch_bounds__(256) void k_scanB(int* __restrict__ part, int n)
{
    __shared__ int tmp[256];
    int t = threadIdx.x;
    int v = (t < n) ? part[t] : 0;
    tmp[t] = v;
    __syncthreads();
    for (int o = 1; o < 256; o <<= 1) {
        int u = (t >= o) ? tmp[t - o] : 0;
        __syncthreads();
        tmp[t] += u;
        __syncthreads();
    }
    if (t < n) part[t] = tmp[t] - v;
}

__global__ __launch_bounds__(256) void k_scanC(
    int* __restrict__ offs, const int* __restrict__ part, int* __restrict__ woffs)
{
    int i = blockIdx.x * 256 + threadIdx.x;
    if (i < NKEY) {
        int v = offs[i] + part[i >> 12];
        offs[i] = v;
        woffs[i] = v;
    } else if (i == NKEY) {
        offs[i] = N_EDGES;
    }
}

__global__ __launch_bounds__(256) void k_fill16(
    const int* __restrict__ src, const int* __restrict__ dst, const int* __restrict__ et,
    int* __restrict__ woffs, unsigned int* __restrict__ csr)
{
    int e = blockIdx.x * 256 + threadIdx.x;
    if (e >= N_EDGES) return;
    int key = dst[e] * 16 + et[e];
    int pos = atomicAdd(&woffs[key], 1);
    csr[pos] = ((unsigned)src[e] << 4) | (unsigned)et[e];
}

// ---------- fused layer: 32 nodes/block, 16 waves (2 nodes each), packed-wt MFMA ----------
__global__ __launch_bounds__(1024, 8) void k_layer(
    const unsigned short* __restrict__ xbf_in,
    const int* __restrict__ offs,
    const unsigned int* __restrict__ csr,
    const unsigned short* __restrict__ wt,    // this layer, packed: [4][34][64][8] bf16
    const float* __restrict__ selfb,          // [64]
    unsigned short* __restrict__ xbf_out)
{
    __shared__ unsigned short S[TILE * SROW];
    const int tid = threadIdx.x, lane = tid & 63, wid = tid >> 6;
    const int nb = blockIdx.x * TILE;

    // issue early: offs + self rows for both nodes of this wave
    int e0s[2], e1s[2];
    unsigned short xselfs[2];
    #pragma unroll
    for (int s = 0; s < 2; ++s) {
        int node = nb + wid * 2 + s;
        bool ok = node < N_NODES;
        int nc = ok ? node : 0;
        int ee0 = offs[nc * 16];
        int ee1 = offs[nc * 16 + 16];
        e0s[s] = ee0;
        e1s[s] = ok ? ee1 : ee0;
        xselfs[s] = ok ? xbf_in[(size_t)nc * 64 + lane] : (unsigned short)0;
    }

    // each wave zeroes its own 2 S rows (elems 0..1087 incl. self slot)
    #pragma unroll
    for (int s = 0; s < 2; ++s) {
        unsigned int* Sr = reinterpret_cast<unsigned int*>(&S[(wid * 2 + s) * SROW]);
        #pragma unroll
        for (int i = 0; i < 8; ++i) Sr[lane + i * 64] = 0u;
        if (lane < 32) Sr[512 + lane] = 0u;
    }

    #pragma unroll 1
    for (int s = 0; s < 2; ++s) {
        const int nl = wid * 2 + s;
        const int e0 = e0s[s], e1 = e1s[s];
        const int degc = e1 - e0;
        const float inv = 1.0f / (float)(degc > 1 ? degc : 1);
        int cur = -1;
        float acc = 0.f;
        for (int base = e0; base < e1; base += 16) {
            const int rem = e1 - base;  // > 0, wave-uniform
            int ci = base + (lane & 15);
            ci = ci < (N_EDGES - 1) ? ci : (N_EDGES - 1);
            const unsigned int ecv = csr[ci];

            unsigned int cv[16];
            float xj[16];
            #pragma unroll
            for (int j = 0; j < 16; ++j) {
                cv[j] = (unsigned)__builtin_amdgcn_readlane((int)ecv, j);
                unsigned sj = (j < rem) ? (cv[j] >> 4) : 0u;  // dummy -> row 0 (L1-hot)
                xj[j] = bf2f(xbf_in[(size_t)sj * 64 + lane]);
            }
            #pragma unroll
            for (int j = 0; j < 16; ++j) {
                if (j < rem) {
                    int rj = (int)(cv[j] & 15u);
                    if (rj != cur) {
                        if (cur >= 0) S[nl * SROW + cur * 64 + lane] = f2bf(acc * inv);
                        cur = rj;
                        acc = 0.f;
                    }
                    acc += xj[j];
                }
            }
        }
        if (cur >= 0) S[nl * SROW + cur * 64 + lane] = f2bf(acc * inv);
        if (nb + nl < N_NODES) S[nl * SROW + 1024 + lane] = xselfs[s];
    }
    __syncthreads();

    // phase B: waves 0..3: cols [wid*16, wid*16+16), two 16-node m-tiles, shared B frags
    if (wid >= 4) return;
    f32x4 acc0 = {0.f, 0.f, 0.f, 0.f};
    f32x4 acc1 = {0.f, 0.f, 0.f, 0.f};
    const int colg = lane & 15, kg = lane >> 4;
    const unsigned short* wb = wt + (size_t)wid * (NKB * 512) + (size_t)lane * 8;
    const unsigned short* s0 = &S[colg * SROW + kg * 8];
    const unsigned short* s1 = &S[(16 + colg) * SROW + kg * 8];
    #pragma unroll 2
    for (int t = 0; t < NKB; ++t) {
        bf16x8 b  = *reinterpret_cast<const bf16x8*>(wb + (size_t)t * 512);
        bf16x8 a0 = *reinterpret_cast<const bf16x8*>(s0 + t * 32);
        bf16x8 a1 = *reinterpret_cast<const bf16x8*>(s1 + t * 32);
        acc0 = __builtin_amdgcn_mfma_f32_16x16x32_bf16(a0, b, acc0, 0, 0, 0);
        acc1 = __builtin_amdgcn_mfma_f32_16x16x32_bf16(a1, b, acc1, 0, 0, 0);
    }
    const int col = wid * 16 + colg;
    const float sb = selfb[col];
    #pragma unroll
    for (int j = 0; j < 4; ++j) {
        int n0 = nb + kg * 4 + j;
        float v0 = acc0[j] + sb;
        v0 = v0 > 0.f ? v0 : 0.f;
        if (n0 < N_NODES) xbf_out[(size_t)n0 * 64 + col] = f2bf(v0);
        int n1 = nb + 16 + kg * 4 + j;
        float v1 = acc1[j] + sb;
        v1 = v1 > 0.f ? v1 : 0.f;
        if (n1 < N_NODES) xbf_out[(size_t)n1 * 64 + col] = f2bf(v1);
    }
}

// ---------- scoring (reads bf16 x) ----------
__global__ __launch_bounds__(256) void k_score(
    const unsigned short* __restrict__ x, const int* __restrict__ heads,
    const int* __restrict__ rels, const int* __restrict__ tails,
    const float* __restrict__ rel_emb, const float* __restrict__ w1,
    const float* __restrict__ b1, const float* __restrict__ w2,
    const float* __restrict__ b2, float* __restrict__ out)
{
    int q = blockIdx.x * 4 + (threadIdx.x >> 6);
    if (q >= N_Q) return;
    int lane = threadIdx.x & 63;
    float zh = bf2f(x[(size_t)heads[q] * 64 + lane]);
    float zt = bf2f(x[(size_t)tails[q] * 64 + lane]);
    float re = rel_emb[(size_t)rels[q] * 64 + lane];
    float acc = b1[lane];
    #pragma unroll 8
    for (int k = 0; k < 64; ++k)
        acc += bcast_lane(zh, k) * w1[k * 64 + lane];
    #pragma unroll 8
    for (int k = 0; k < 64; ++k)
        acc += bcast_lane(zt, k) * w1[(64 + k) * 64 + lane];
    #pragma unroll 8
    for (int k = 0; k < 64; ++k)
        acc += bcast_lane(re, k) * w1[(128 + k) * 64 + lane];
    float h = acc > 0.f ? acc : 0.f;
    float p = h * w2[lane];
    #pragma unroll
    for (int off = 32; off > 0; off >>= 1) p += __shfl_xor(p, off);
    if (lane == 0) out[q] = p + b2[0];
}

// ---------- launch ----------
extern "C" void kernel_launch(void* const* d_in, const int* in_sizes, int n_in,
                              void* d_out, int out_size, void* d_ws, size_t ws_size,
                              hipStream_t stream)
{
    const float* node_feat = (const float*)d_in[0];
    const int* edge_index  = (const int*)d_in[1];
    const int* edge_type   = (const int*)d_in[2];
    const int* heads       = (const int*)d_in[3];
    const int* rels        = (const int*)d_in[4];
    const int* tails       = (const int*)d_in[5];
    const float* in_w      = (const float*)d_in[6];
    const float* in_b      = (const float*)d_in[7];
    const float* rel_w     = (const float*)d_in[8];
    const float* self_w    = (const float*)d_in[9];
    const float* self_b    = (const float*)d_in[10];
    const float* rel_emb   = (const float*)d_in[11];
    const float* sc_w1     = (const float*)d_in[12];
    const float* sc_b1     = (const float*)d_in[13];
    const float* sc_w2     = (const float*)d_in[14];
    const float* sc_b2     = (const float*)d_in[15];
    float* out = (float*)d_out;

    char* ws = (char*)d_ws;
    size_t off = 0;
    auto alloc = [&](size_t bytes) -> void* {
        void* p = ws + off;
        off = (off + bytes + 255) & ~(size_t)255;
        return p;
    };
    unsigned short* xbf_a = (unsigned short*)alloc((size_t)N_NODES * 64 * 2);
    unsigned short* xbf_b = (unsigned short*)alloc((size_t)N_NODES * 64 * 2);
    int* cnt              = (int*)alloc((size_t)NKEY * 4);
    int* offs             = (int*)alloc((size_t)(NKEY + 1) * 4);
    int* woffs            = (int*)alloc((size_t)NKEY * 4);
    unsigned int* csr     = (unsigned int*)alloc((size_t)N_EDGES * 4);
    unsigned short* wt    = (unsigned short*)alloc((size_t)2 * WTL * 2);
    int* part             = (int*)alloc(1024);

    const int* src = edge_index;
    const int* dst = edge_index + N_EDGES;

    const int nscan = (NKEY + 4095) / 4096;  // 196

    hipMemsetAsync(cnt, 0, (size_t)NKEY * 4, stream);
    k_input_proj<<<(N_NODES * 64 + 255) / 256, 256, 0, stream>>>(node_feat, in_w, in_b, xbf_a);
    k_wprep<<<(2 * WTL + 255) / 256, 256, 0, stream>>>(rel_w, self_w, wt);
    k_hist16<<<(N_EDGES + 255) / 256, 256, 0, stream>>>(dst, edge_type, cnt);
    k_scanA<<<nscan, 256, 0, stream>>>(cnt, offs, part);
    k_scanB<<<1, 256, 0, stream>>>(part, nscan);
    k_scanC<<<(NKEY + 1 + 255) / 256, 256, 0, stream>>>(offs, part, woffs);
    k_fill16<<<(N_EDGES + 255) / 256, 256, 0, stream>>>(src, dst, edge_type, woffs, csr);

    for (int l = 0; l < 2; ++l) {
        const unsigned short* xin = (l == 0) ? xbf_a : xbf_b;
        unsigned short* xout = (l == 0) ? xbf_b : xbf_a;
        k_layer<<<(N_NODES + TILE - 1) / TILE, 1024, 0, stream>>>(
            xin, offs, csr, wt + (size_t)l * WTL, self_b + l * 64, xout);
    }
    k_score<<<(N_Q + 3) / 4, 256, 0, stream>>>(xbf_a, heads, rels, tails, rel_emb,
                                               sc_w1, sc_b1, sc_w2, sc_b2, out);
}

// Round 7
// 222.704 us; speedup vs baseline: 2.4852x; 1.0583x over previous
//
#include <hip/hip_runtime.h>
#include <hip/hip_bf16.h>
#include <cstdint>
#include <cstddef>

#define N_NODES 50000
#define N_EDGES 800000
#define DIM 64
#define N_REL 16
#define N_Q 8192
#define NKEY (N_NODES * 16)
#define KDIM 1088   // 16 relations * 64 + 64 self
#define SROW 1096   // padded LDS row in bf16 elems
#define TILE 32     // nodes per block (2 per wave)
#define NKB 34      // K blocks of 32 (KDIM/32)
#define KH 17       // kblocks per k-half
#define WTL (4 * NKB * 512)  // per-layer packed wt elems

typedef __attribute__((ext_vector_type(8))) short bf16x8;
typedef __attribute__((ext_vector_type(4))) float f32x4;

__device__ __forceinline__ float bcast_lane(float v, int l) {
    return __int_as_float(__builtin_amdgcn_readlane(__float_as_int(v), l));
}
__device__ __forceinline__ unsigned short f2bf(float f) {
    unsigned int b = __float_as_uint(f);
    return (unsigned short)((b + 0x7FFFu + ((b >> 16) & 1u)) >> 16);
}
__device__ __forceinline__ float bf2f(unsigned short u) {
    return __uint_as_float(((unsigned int)u) << 16);
}

// ---------- input projection -> bf16 x ----------
__global__ __launch_bounds__(256) void k_input_proj(
    const float* __restrict__ nf, const float* __restrict__ inw,
    const float* __restrict__ inb, unsigned short* __restrict__ xbf)
{
    int t = blockIdx.x * 256 + threadIdx.x;
    if (t >= N_NODES * 64) return;
    int n = t >> 6, o = t & 63;
    float4 f = *reinterpret_cast<const float4*>(nf + (size_t)n * 4);
    float a = inb[o] + f.x * inw[o] + f.y * inw[64 + o] + f.z * inw[128 + o] + f.w * inw[192 + o];
    xbf[t] = f2bf(a > 0.f ? a : 0.f);
}

// ---------- weight prep: packed MFMA B-fragment order ----------
// wtp[l][g][t][lane][j] = W[k = t*32 + (lane>>4)*8 + j][col = g*16 + (lane&15)]
__global__ __launch_bounds__(256) void k_wprep(
    const float* __restrict__ rel_w, const float* __restrict__ self_w,
    unsigned short* __restrict__ wt)
{
    int i = blockIdx.x * 256 + threadIdx.x;
    if (i >= 2 * WTL) return;
    int j = i & 7;
    int lane = (i >> 3) & 63;
    int rest = i >> 9;          // l*136 + g*34 + t
    int t = rest % NKB;
    int gl = rest / NKB;
    int g = gl & 3;
    int l = gl >> 2;
    int col = g * 16 + (lane & 15);
    int k = t * 32 + (lane >> 4) * 8 + j;
    float v;
    if (k < 1024) {
        int r = k >> 6, d = k & 63;
        v = rel_w[(((size_t)l * 16 + r) * 64 + d) * 64 + col];
    } else {
        int d = k - 1024;
        v = self_w[((size_t)l * 64 + d) * 64 + col];
    }
    wt[i] = f2bf(v);
}

// ---------- CSR build over key = dst*16 + rel ----------
__global__ __launch_bounds__(256) void k_hist16(
    const int* __restrict__ dst, const int* __restrict__ et, int* __restrict__ cnt)
{
    int e = blockIdx.x * 256 + threadIdx.x;
    if (e < N_EDGES) atomicAdd(&cnt[dst[e] * 16 + et[e]], 1);
}

__global__ __launch_bounds__(256) void k_scanA(
    const int* __restrict__ cnt, int* __restrict__ offs, int* __restrict__ part)
{
    int t = threadIdx.x;
    size_t base = (size_t)blockIdx.x * 4096 + (size_t)t * 16;
    bool ok = base < (size_t)NKEY;
    int v[16];
    if (ok) {
        #pragma unroll
        for (int q = 0; q < 4; ++q)
            *reinterpret_cast<int4*>(&v[q * 4]) = *reinterpret_cast<const int4*>(&cnt[base + q * 4]);
    } else {
        #pragma unroll
        for (int j = 0; j < 16; ++j) v[j] = 0;
    }
    int run = 0;
    #pragma unroll
    for (int j = 0; j < 16; ++j) { int c = v[j]; v[j] = run; run += c; }
    int lane = t & 63, wid = t >> 6;
    int incl = run;
    #pragma unroll
    for (int o = 1; o < 64; o <<= 1) { int u = __shfl_up(incl, o); if (lane >= o) incl += u; }
    __shared__ int wtot[4], wbase[4];
    if (lane == 63) wtot[wid] = incl;
    __syncthreads();
    if (t == 0) { int r = 0; for (int w = 0; w < 4; ++w) { wbase[w] = r; r += wtot[w]; } part[blockIdx.x] = r; }
    __syncthreads();
    int texcl = wbase[wid] + incl - run;
    if (ok) {
        #pragma unroll
        for (int j = 0; j < 16; ++j) offs[base + j] = texcl + v[j];
    }
}

__global__ __launch_bounds__(256) void k_scanB(int* __restrict__ part, int n)
{
    __shared__ int tmp[256];
    int t = threadIdx.x;
    int v = (t < n) ? part[t] : 0;
    tmp[t] = v;
    __syncthreads();
    for (int o = 1; o < 256; o <<= 1) {
        int u = (t >= o) ? tmp[t - o] : 0;
        __syncthreads();
        tmp[t] += u;
        __syncthreads();
    }
    if (t < n) part[t] = tmp[t] - v;
}

__global__ __launch_bounds__(256) void k_scanC(
    int* __restrict__ offs, const int* __restrict__ part, int* __restrict__ woffs)
{
    int i = blockIdx.x * 256 + threadIdx.x;
    if (i < NKEY) {
        int v = offs[i] + part[i >> 12];
        offs[i] = v;
        woffs[i] = v;
    } else if (i == NKEY) {
        offs[i] = N_EDGES;
    }
}

__global__ __launch_bounds__(256) void k_fill16(
    const int* __restrict__ src, const int* __restrict__ dst, const int* __restrict__ et,
    int* __restrict__ woffs, unsigned int* __restrict__ csr)
{
    int e = blockIdx.x * 256 + threadIdx.x;
    if (e >= N_EDGES) return;
    int key = dst[e] * 16 + et[e];
    int pos = atomicAdd(&woffs[key], 1);
    csr[pos] = ((unsigned)src[e] << 4) | (unsigned)et[e];
}

// ---------- fused layer: 32 nodes/block, 16 waves; scalarized gather; 16-wave MFMA ----------
__global__ __launch_bounds__(1024, 8) void k_layer(
    const unsigned short* __restrict__ xbf_in,
    const int* __restrict__ offs,
    const unsigned int* __restrict__ csr,
    const unsigned short* __restrict__ wt,    // this layer, packed: [4][34][64][8] bf16
    const float* __restrict__ selfb,          // [64]
    unsigned short* __restrict__ xbf_out)
{
    alignas(16) __shared__ unsigned short S[TILE * SROW];
    const int tid = threadIdx.x, lane = tid & 63;
    // wave-uniform wid in SGPR -> everything derived is scalar (s_load for offs/csr)
    const int wid = __builtin_amdgcn_readfirstlane(tid >> 6);
    const int nb = blockIdx.x * TILE;

    // zero own 2 S rows (elems 0..1087 incl. self slot)
    #pragma unroll
    for (int s = 0; s < 2; ++s) {
        unsigned int* Sr = reinterpret_cast<unsigned int*>(&S[(wid * 2 + s) * SROW]);
        #pragma unroll
        for (int i = 0; i < 8; ++i) Sr[lane + i * 64] = 0u;
        if (lane < 32) Sr[512 + lane] = 0u;
    }

    // phase A: gather-accumulate, scalar control path
    #pragma unroll 1
    for (int s = 0; s < 2; ++s) {
        const int nl = wid * 2 + s;
        const int node = nb + nl;
        if (node >= N_NODES) break;
        const int e0 = offs[node * 16];
        const int e1 = offs[node * 16 + 16];
        S[nl * SROW + 1024 + lane] = xbf_in[(size_t)node * 64 + lane];
        const int degc = e1 - e0;
        if (degc <= 0) continue;
        const float inv = 1.0f / (float)(degc > 1 ? degc : 1);
        int cur = -1;
        float acc = 0.f;
        int e = e0;
        while (e < e1) {
            int m = e1 - e;
            m = m > 8 ? 8 : m;
            unsigned cvs[8];
            if (m == 8) {
                #pragma unroll
                for (int j = 0; j < 8; ++j) cvs[j] = csr[e + j];
            } else {
                #pragma unroll
                for (int j = 0; j < 8; ++j) cvs[j] = csr[e + (j < m ? j : m - 1)];
            }
            float xv[8];
            #pragma unroll
            for (int j = 0; j < 8; ++j)
                xv[j] = bf2f(xbf_in[(size_t)(cvs[j] >> 4) * 64 + lane]);
            #pragma unroll
            for (int j = 0; j < 8; ++j) {
                if (j < m) {
                    int rj = (int)(cvs[j] & 15u);
                    if (rj != cur) {
                        if (cur >= 0) S[nl * SROW + cur * 64 + lane] = f2bf(acc * inv);
                        cur = rj;
                        acc = 0.f;
                    }
                    acc += xv[j];
                }
            }
            e += m;
        }
        if (cur >= 0) S[nl * SROW + cur * 64 + lane] = f2bf(acc * inv);
    }
    __syncthreads();

    // phase B: 16 waves: (colgroup g, mtile m, khalf kh); 17 kblocks each
    const int g = wid & 3, mt = (wid >> 2) & 1, kh = wid >> 3;
    const int colg = lane & 15, kg = lane >> 4;
    f32x4 acc4 = {0.f, 0.f, 0.f, 0.f};
    const unsigned short* wb = wt + (size_t)g * (NKB * 512) + (size_t)lane * 8 + (size_t)kh * KH * 512;
    const unsigned short* sa = &S[(mt * 16 + colg) * SROW + kg * 8 + kh * KH * 32];
    #pragma unroll 2
    for (int t = 0; t < KH; ++t) {
        bf16x8 b = *reinterpret_cast<const bf16x8*>(wb + (size_t)t * 512);
        bf16x8 a = *reinterpret_cast<const bf16x8*>(sa + t * 32);
        acc4 = __builtin_amdgcn_mfma_f32_16x16x32_bf16(a, b, acc4, 0, 0, 0);
    }
    __syncthreads();
    float4* scratch = reinterpret_cast<float4*>(S);
    if (kh == 1) {
        scratch[(wid - 8) * 64 + lane] = make_float4(acc4[0], acc4[1], acc4[2], acc4[3]);
    }
    __syncthreads();
    if (kh == 0) {
        float4 p = scratch[wid * 64 + lane];
        const int col = g * 16 + colg;
        const float sb = selfb[col];
        float vj[4] = {acc4[0] + p.x, acc4[1] + p.y, acc4[2] + p.z, acc4[3] + p.w};
        #pragma unroll
        for (int j = 0; j < 4; ++j) {
            int n0 = nb + mt * 16 + kg * 4 + j;
            float v = vj[j] + sb;
            v = v > 0.f ? v : 0.f;
            if (n0 < N_NODES) xbf_out[(size_t)n0 * 64 + col] = f2bf(v);
        }
    }
}

// ---------- scoring (reads bf16 x) ----------
__global__ __launch_bounds__(256) void k_score(
    const unsigned short* __restrict__ x, const int* __restrict__ heads,
    const int* __restrict__ rels, const int* __restrict__ tails,
    const float* __restrict__ rel_emb, const float* __restrict__ w1,
    const float* __restrict__ b1, const float* __restrict__ w2,
    const float* __restrict__ b2, float* __restrict__ out)
{
    int q = blockIdx.x * 4 + (threadIdx.x >> 6);
    if (q >= N_Q) return;
    int lane = threadIdx.x & 63;
    float zh = bf2f(x[(size_t)heads[q] * 64 + lane]);
    float zt = bf2f(x[(size_t)tails[q] * 64 + lane]);
    float re = rel_emb[(size_t)rels[q] * 64 + lane];
    float acc = b1[lane];
    #pragma unroll 8
    for (int k = 0; k < 64; ++k)
        acc += bcast_lane(zh, k) * w1[k * 64 + lane];
    #pragma unroll 8
    for (int k = 0; k < 64; ++k)
        acc += bcast_lane(zt, k) * w1[(64 + k) * 64 + lane];
    #pragma unroll 8
    for (int k = 0; k < 64; ++k)
        acc += bcast_lane(re, k) * w1[(128 + k) * 64 + lane];
    float h = acc > 0.f ? acc : 0.f;
    float p = h * w2[lane];
    #pragma unroll
    for (int off = 32; off > 0; off >>= 1) p += __shfl_xor(p, off);
    if (lane == 0) out[q] = p + b2[0];
}

// ---------- launch ----------
extern "C" void kernel_launch(void* const* d_in, const int* in_sizes, int n_in,
                              void* d_out, int out_size, void* d_ws, size_t ws_size,
                              hipStream_t stream)
{
    const float* node_feat = (const float*)d_in[0];
    const int* edge_index  = (const int*)d_in[1];
    const int* edge_type   = (const int*)d_in[2];
    const int* heads       = (const int*)d_in[3];
    const int* rels        = (const int*)d_in[4];
    const int* tails       = (const int*)d_in[5];
    const float* in_w      = (const float*)d_in[6];
    const float* in_b      = (const float*)d_in[7];
    const float* rel_w     = (const float*)d_in[8];
    const float* self_w    = (const float*)d_in[9];
    const float* self_b    = (const float*)d_in[10];
    const float* rel_emb   = (const float*)d_in[11];
    const float* sc_w1     = (const float*)d_in[12];
    const float* sc_b1     = (const float*)d_in[13];
    const float* sc_w2     = (const float*)d_in[14];
    const float* sc_b2     = (const float*)d_in[15];
    float* out = (float*)d_out;

    char* ws = (char*)d_ws;
    size_t off = 0;
    auto alloc = [&](size_t bytes) -> void* {
        void* p = ws + off;
        off = (off + bytes + 255) & ~(size_t)255;
        return p;
    };
    unsigned short* xbf_a = (unsigned short*)alloc((size_t)N_NODES * 64 * 2);
    unsigned short* xbf_b = (unsigned short*)alloc((size_t)N_NODES * 64 * 2);
    int* cnt              = (int*)alloc((size_t)NKEY * 4);
    int* offs             = (int*)alloc((size_t)(NKEY + 1) * 4);
    int* woffs            = (int*)alloc((size_t)NKEY * 4);
    unsigned int* csr     = (unsigned int*)alloc((size_t)N_EDGES * 4);
    unsigned short* wt    = (unsigned short*)alloc((size_t)2 * WTL * 2);
    int* part             = (int*)alloc(1024);

    const int* src = edge_index;
    const int* dst = edge_index + N_EDGES;

    const int nscan = (NKEY + 4095) / 4096;  // 196

    hipMemsetAsync(cnt, 0, (size_t)NKEY * 4, stream);
    k_input_proj<<<(N_NODES * 64 + 255) / 256, 256, 0, stream>>>(node_feat, in_w, in_b, xbf_a);
    k_wprep<<<(2 * WTL + 255) / 256, 256, 0, stream>>>(rel_w, self_w, wt);
    k_hist16<<<(N_EDGES + 255) / 256, 256, 0, stream>>>(dst, edge_type, cnt);
    k_scanA<<<nscan, 256, 0, stream>>>(cnt, offs, part);
    k_scanB<<<1, 256, 0, stream>>>(part, nscan);
    k_scanC<<<(NKEY + 1 + 255) / 256, 256, 0, stream>>>(offs, part, woffs);
    k_fill16<<<(N_EDGES + 255) / 256, 256, 0, stream>>>(src, dst, edge_type, woffs, csr);

    for (int l = 0; l < 2; ++l) {
        const unsigned short* xin = (l == 0) ? xbf_a : xbf_b;
        unsigned short* xout = (l == 0) ? xbf_b : xbf_a;
        k_layer<<<(N_NODES + TILE - 1) / TILE, 1024, 0, stream>>>(
            xin, offs, csr, wt + (size_t)l * WTL, self_b + l * 64, xout);
    }
    k_score<<<(N_Q + 3) / 4, 256, 0, stream>>>(xbf_a, heads, rels, tails, rel_emb,
                                               sc_w1, sc_b1, sc_w2, sc_b2, out);
}